// Round 1
// baseline (12271.004 us; speedup 1.0000x reference)
//
#include <hip/hip_runtime.h>

#define USER_NUM 100000
#define ITEM_NUM 50000
#define N_NODES  150000   // USER_NUM + ITEM_NUM
#define EMB_DIM  64
#define NNZ      4800000
#define N_VEC4   (N_NODES * (EMB_DIM / 4))   // 2.4M float4 elements

// ---------------------------------------------------------------------------
// init: ego = concat(user_emb, item_emb); acc (= d_out) = ego
// ---------------------------------------------------------------------------
__global__ void lgcn_init(const float4* __restrict__ user,
                          const float4* __restrict__ item,
                          float4* __restrict__ ego,
                          float4* __restrict__ acc) {
    int i = blockIdx.x * blockDim.x + threadIdx.x;
    if (i >= N_VEC4) return;
    const int user_elems = USER_NUM * (EMB_DIM / 4);
    float4 v = (i < user_elems) ? user[i] : item[i - user_elems];
    ego[i] = v;
    acc[i] = v;
}

// ---------------------------------------------------------------------------
// SpMM: y[row[e]] += vals[e] * x[col[e]]   (atomic scatter)
// 16 threads per edge; each thread handles one float4 chunk (4 floats).
// Wave of 64 lanes covers 4 edges; per-edge addresses are 256B-contiguous.
// ---------------------------------------------------------------------------
__global__ void lgcn_spmm_atomic(const int*   __restrict__ row,
                                 const int*   __restrict__ col,
                                 const float* __restrict__ vals,
                                 const float* __restrict__ x,
                                 float*       __restrict__ y) {
    long long tid = (long long)blockIdx.x * blockDim.x + threadIdx.x;
    long long e = tid >> 4;          // edge index
    if (e >= NNZ) return;
    int c = (int)(tid & 15);         // float4 chunk within the 64-dim row

    int   r  = row[e];
    int   cl = col[e];
    float v  = vals[e];

    const float4* xs = (const float4*)(x + (long long)cl * EMB_DIM);
    float4 xv = xs[c];

    float* yb = y + (long long)r * EMB_DIM + c * 4;
    atomicAdd(yb + 0, v * xv.x);
    atomicAdd(yb + 1, v * xv.y);
    atomicAdd(yb + 2, v * xv.z);
    atomicAdd(yb + 3, v * xv.w);
}

// ---------------------------------------------------------------------------
// acc = (acc + ego) * scale     (scale=1 for layers 0,1; 0.25 folded into last)
// ---------------------------------------------------------------------------
__global__ void lgcn_acc_add(float4* __restrict__ acc,
                             const float4* __restrict__ ego,
                             float scale) {
    int i = blockIdx.x * blockDim.x + threadIdx.x;
    if (i >= N_VEC4) return;
    float4 a = acc[i];
    float4 e = ego[i];
    a.x = (a.x + e.x) * scale;
    a.y = (a.y + e.y) * scale;
    a.z = (a.z + e.z) * scale;
    a.w = (a.w + e.w) * scale;
    acc[i] = a;
}

extern "C" void kernel_launch(void* const* d_in, const int* in_sizes, int n_in,
                              void* d_out, int out_size, void* d_ws, size_t ws_size,
                              hipStream_t stream) {
    const float* user_emb = (const float*)d_in[0];
    const float* item_emb = (const float*)d_in[1];
    const int*   adj_row  = (const int*)d_in[2];
    const int*   adj_col  = (const int*)d_in[3];
    const float* adj_vals = (const float*)d_in[4];
    float* out = (float*)d_out;

    const size_t mat_bytes = (size_t)N_NODES * EMB_DIM * sizeof(float); // 38.4 MB
    float* ego_a = (float*)d_ws;                                  // current layer input
    float* ego_b = (float*)((char*)d_ws + mat_bytes);             // spmm output

    // init: ego_a = concat(user,item); out (acc) = same
    {
        int threads = 256;
        int blocks = (N_VEC4 + threads - 1) / threads;
        lgcn_init<<<blocks, threads, 0, stream>>>(
            (const float4*)user_emb, (const float4*)item_emb,
            (float4*)ego_a, (float4*)out);
    }

    const long long spmm_threads_total = (long long)NNZ * 16;
    const int spmm_block = 256;
    const int spmm_grid  = (int)((spmm_threads_total + spmm_block - 1) / spmm_block);
    const int ew_block = 256;
    const int ew_grid  = (N_VEC4 + ew_block - 1) / ew_block;

    for (int layer = 0; layer < 3; ++layer) {
        // zero the spmm output buffer
        hipMemsetAsync(ego_b, 0, mat_bytes, stream);

        lgcn_spmm_atomic<<<spmm_grid, spmm_block, 0, stream>>>(
            adj_row, adj_col, adj_vals, ego_a, ego_b);

        float scale = (layer == 2) ? 0.25f : 1.0f;
        lgcn_acc_add<<<ew_grid, ew_block, 0, stream>>>(
            (float4*)out, (const float4*)ego_b, scale);

        // swap ego buffers
        float* t = ego_a; ego_a = ego_b; ego_b = t;
    }
}

// Round 2
// 1194.120 us; speedup vs baseline: 10.2762x; 10.2762x over previous
//
#include <hip/hip_runtime.h>

#define USER_NUM 100000
#define ITEM_NUM 50000
#define N_NODES  150000   // USER_NUM + ITEM_NUM
#define EMB_DIM  64
#define NNZ      4800000
#define N_VEC4   (N_NODES * (EMB_DIM / 4))   // 2.4M float4 elements

#define SCAN_ITEMS 1024
#define NUM_SCAN_BLOCKS ((N_NODES + SCAN_ITEMS - 1) / SCAN_ITEMS)  // 147

// ---------------------------------------------------------------------------
// init: ego = concat(user_emb, item_emb); acc (= d_out) = ego
// ---------------------------------------------------------------------------
__global__ void lgcn_init(const float4* __restrict__ user,
                          const float4* __restrict__ item,
                          float4* __restrict__ ego,
                          float4* __restrict__ acc) {
    int i = blockIdx.x * blockDim.x + threadIdx.x;
    if (i >= N_VEC4) return;
    const int user_elems = USER_NUM * (EMB_DIM / 4);
    float4 v = (i < user_elems) ? user[i] : item[i - user_elems];
    ego[i] = v;
    acc[i] = v;
}

// ---------------------------------------------------------------------------
// CSR build step 1: histogram of row indices
// ---------------------------------------------------------------------------
__global__ void lgcn_hist(const int* __restrict__ row, int* __restrict__ cnt) {
    int e = blockIdx.x * blockDim.x + threadIdx.x;
    if (e >= NNZ) return;
    atomicAdd(&cnt[row[e]], 1);
}

// ---------------------------------------------------------------------------
// CSR build step 2a: per-block sums of cnt (1024 elements / block)
// ---------------------------------------------------------------------------
__global__ void lgcn_scan_blocksums(const int* __restrict__ cnt,
                                    int* __restrict__ blockSum) {
    int b = blockIdx.x, t = threadIdx.x;
    int base = b * SCAN_ITEMS + t * 4;
    int s = 0;
#pragma unroll
    for (int k = 0; k < 4; ++k) {
        int i = base + k;
        if (i < N_NODES) s += cnt[i];
    }
    __shared__ int red[256];
    red[t] = s;
    __syncthreads();
    for (int off = 128; off > 0; off >>= 1) {
        if (t < off) red[t] += red[t + off];
        __syncthreads();
    }
    if (t == 0) blockSum[b] = red[0];
}

// ---------------------------------------------------------------------------
// CSR build step 2b: exclusive scan of block sums (single block)
// ---------------------------------------------------------------------------
__global__ void lgcn_scan_sums(const int* __restrict__ blockSum,
                               int* __restrict__ blockBase,
                               int* __restrict__ row_ptr) {
    int t = threadIdx.x;
    __shared__ int s[256];
    int v = (t < NUM_SCAN_BLOCKS) ? blockSum[t] : 0;
    s[t] = v;
    __syncthreads();
    for (int off = 1; off < 256; off <<= 1) {
        int x = (t >= off) ? s[t - off] : 0;
        __syncthreads();
        s[t] += x;
        __syncthreads();
    }
    if (t < NUM_SCAN_BLOCKS) blockBase[t] = s[t] - v;  // exclusive
    if (t == 0) row_ptr[N_NODES] = NNZ;
}

// ---------------------------------------------------------------------------
// CSR build step 2c: final exclusive scan -> row_ptr[0..N_NODES)
// ---------------------------------------------------------------------------
__global__ void lgcn_scan_final(const int* __restrict__ cnt,
                                const int* __restrict__ blockBase,
                                int* __restrict__ row_ptr) {
    int b = blockIdx.x, t = threadIdx.x;
    int base = b * SCAN_ITEMS + t * 4;
    int v[4];
    int tsum = 0;
#pragma unroll
    for (int k = 0; k < 4; ++k) {
        int i = base + k;
        v[k] = (i < N_NODES) ? cnt[i] : 0;
        tsum += v[k];
    }
    __shared__ int s[256];
    s[t] = tsum;
    __syncthreads();
    for (int off = 1; off < 256; off <<= 1) {
        int x = (t >= off) ? s[t - off] : 0;
        __syncthreads();
        s[t] += x;
        __syncthreads();
    }
    int p = blockBase[b] + (s[t] - tsum);  // exclusive prefix for this thread
#pragma unroll
    for (int k = 0; k < 4; ++k) {
        int i = base + k;
        if (i < N_NODES) row_ptr[i] = p;
        p += v[k];
    }
}

// ---------------------------------------------------------------------------
// CSR build step 3: scatter (col, val) into CSR order
// ---------------------------------------------------------------------------
__global__ void lgcn_scatter(const int* __restrict__ row,
                             const int* __restrict__ col,
                             const float* __restrict__ vals,
                             const int* __restrict__ row_ptr,
                             int* __restrict__ cursor,
                             int* __restrict__ csr_col,
                             float* __restrict__ csr_val) {
    int e = blockIdx.x * blockDim.x + threadIdx.x;
    if (e >= NNZ) return;
    int r = row[e];
    int pos = row_ptr[r] + atomicAdd(&cursor[r], 1);
    csr_col[pos] = col[e];
    csr_val[pos] = vals[e];
}

// ---------------------------------------------------------------------------
// SpMM (pure gather): one wave per row. Lanes = 4 edge-subgroups x 16 chunks.
// Fused epilogue: y = A@x row; acc = (acc + y) * scale.
// ---------------------------------------------------------------------------
__global__ __launch_bounds__(256) void lgcn_spmm_csr(
    const int* __restrict__ row_ptr,
    const int* __restrict__ csr_col,
    const float* __restrict__ csr_val,
    const float* __restrict__ x,
    float4* __restrict__ y,
    float4* __restrict__ acc,
    float scale) {
    int gid = blockIdx.x * blockDim.x + threadIdx.x;
    int r = gid >> 6;
    if (r >= N_NODES) return;
    int lane = threadIdx.x & 63;
    int chunk = lane & 15;   // which float4 of the 64-dim row
    int sub = lane >> 4;     // edge subgroup 0..3

    int start = row_ptr[r];
    int end = row_ptr[r + 1];

    float4 a = make_float4(0.f, 0.f, 0.f, 0.f);
    const float4* x4 = (const float4*)x;
    for (int e = start + sub; e < end; e += 4) {
        int c = csr_col[e];
        float v = csr_val[e];
        float4 xv = x4[c * 16 + chunk];
        a.x += v * xv.x;
        a.y += v * xv.y;
        a.z += v * xv.z;
        a.w += v * xv.w;
    }

    // reduce across the 4 edge subgroups (lanes differing in bits 4,5)
    a.x += __shfl_xor(a.x, 16); a.y += __shfl_xor(a.y, 16);
    a.z += __shfl_xor(a.z, 16); a.w += __shfl_xor(a.w, 16);
    a.x += __shfl_xor(a.x, 32); a.y += __shfl_xor(a.y, 32);
    a.z += __shfl_xor(a.z, 32); a.w += __shfl_xor(a.w, 32);

    if (sub == 0) {
        int idx = r * 16 + chunk;
        y[idx] = a;
        float4 o = acc[idx];
        o.x = (o.x + a.x) * scale;
        o.y = (o.y + a.y) * scale;
        o.z = (o.z + a.z) * scale;
        o.w = (o.w + a.w) * scale;
        acc[idx] = o;
    }
}

extern "C" void kernel_launch(void* const* d_in, const int* in_sizes, int n_in,
                              void* d_out, int out_size, void* d_ws, size_t ws_size,
                              hipStream_t stream) {
    const float* user_emb = (const float*)d_in[0];
    const float* item_emb = (const float*)d_in[1];
    const int*   adj_row  = (const int*)d_in[2];
    const int*   adj_col  = (const int*)d_in[3];
    const float* adj_vals = (const float*)d_in[4];
    float* out = (float*)d_out;

    // workspace layout (~116.4 MB total)
    float* ego_a   = (float*)d_ws;                       // 38.4 MB
    float* ego_b   = ego_a + (size_t)N_NODES * EMB_DIM;  // 38.4 MB
    int*   cnt     = (int*)(ego_b + (size_t)N_NODES * EMB_DIM);  // 600 KB
    int*   row_ptr = cnt + N_NODES;                      // 600 KB
    int*   blockSum  = row_ptr + (N_NODES + 1);          // 1 KB
    int*   blockBase = blockSum + 256;                   // 1 KB
    int*   csr_col = blockBase + 256;                    // 19.2 MB
    float* csr_val = (float*)(csr_col + NNZ);            // 19.2 MB

    // init: ego_a = concat(user,item); out (acc) = same
    {
        int threads = 256;
        int blocks = (N_VEC4 + threads - 1) / threads;
        lgcn_init<<<blocks, threads, 0, stream>>>(
            (const float4*)user_emb, (const float4*)item_emb,
            (float4*)ego_a, (float4*)out);
    }

    // ---- CSR build ----
    hipMemsetAsync(cnt, 0, (size_t)N_NODES * sizeof(int), stream);
    {
        int threads = 256;
        int blocks = (NNZ + threads - 1) / threads;
        lgcn_hist<<<blocks, threads, 0, stream>>>(adj_row, cnt);
    }
    lgcn_scan_blocksums<<<NUM_SCAN_BLOCKS, 256, 0, stream>>>(cnt, blockSum);
    lgcn_scan_sums<<<1, 256, 0, stream>>>(blockSum, blockBase, row_ptr);
    lgcn_scan_final<<<NUM_SCAN_BLOCKS, 256, 0, stream>>>(cnt, blockBase, row_ptr);
    hipMemsetAsync(cnt, 0, (size_t)N_NODES * sizeof(int), stream);  // reuse as cursor
    {
        int threads = 256;
        int blocks = (NNZ + threads - 1) / threads;
        lgcn_scatter<<<blocks, threads, 0, stream>>>(
            adj_row, adj_col, adj_vals, row_ptr, cnt, csr_col, csr_val);
    }

    // ---- 3 propagation layers (pure-gather SpMM, fused acc update) ----
    const int spmm_block = 256;                       // 4 waves = 4 rows / block
    const int spmm_grid = (N_NODES * 64 + spmm_block - 1) / spmm_block;
    for (int layer = 0; layer < 3; ++layer) {
        float scale = (layer == 2) ? 0.25f : 1.0f;
        lgcn_spmm_csr<<<spmm_grid, spmm_block, 0, stream>>>(
            row_ptr, csr_col, csr_val, ego_a,
            (float4*)ego_b, (float4*)out, scale);
        float* t = ego_a; ego_a = ego_b; ego_b = t;
    }
}

// Round 3
// 1063.982 us; speedup vs baseline: 11.5331x; 1.1223x over previous
//
#include <hip/hip_runtime.h>

#define USER_NUM 100000
#define ITEM_NUM 50000
#define N_NODES  150000   // USER_NUM + ITEM_NUM
#define EMB_DIM  64
#define NNZ      4800000
#define N_VEC4   (N_NODES * (EMB_DIM / 4))   // 2.4M float4 elements

#define SCAN_ITEMS 1024
#define NUM_SCAN_BLOCKS ((N_NODES + SCAN_ITEMS - 1) / SCAN_ITEMS)  // 147

// ---------------------------------------------------------------------------
// init: ego = concat(user_emb, item_emb); acc (= d_out) = ego
// ---------------------------------------------------------------------------
__global__ void lgcn_init(const float4* __restrict__ user,
                          const float4* __restrict__ item,
                          float4* __restrict__ ego,
                          float4* __restrict__ acc) {
    int i = blockIdx.x * blockDim.x + threadIdx.x;
    if (i >= N_VEC4) return;
    const int user_elems = USER_NUM * (EMB_DIM / 4);
    float4 v = (i < user_elems) ? user[i] : item[i - user_elems];
    ego[i] = v;
    acc[i] = v;
}

// ---------------------------------------------------------------------------
// CSR build step 1: histogram of row indices
// ---------------------------------------------------------------------------
__global__ void lgcn_hist(const int* __restrict__ row, int* __restrict__ cnt) {
    int e = blockIdx.x * blockDim.x + threadIdx.x;
    if (e >= NNZ) return;
    atomicAdd(&cnt[row[e]], 1);
}

// ---------------------------------------------------------------------------
// CSR build step 2a: per-block sums of cnt (1024 elements / block)
// ---------------------------------------------------------------------------
__global__ void lgcn_scan_blocksums(const int* __restrict__ cnt,
                                    int* __restrict__ blockSum) {
    int b = blockIdx.x, t = threadIdx.x;
    int base = b * SCAN_ITEMS + t * 4;
    int s = 0;
#pragma unroll
    for (int k = 0; k < 4; ++k) {
        int i = base + k;
        if (i < N_NODES) s += cnt[i];
    }
    __shared__ int red[256];
    red[t] = s;
    __syncthreads();
    for (int off = 128; off > 0; off >>= 1) {
        if (t < off) red[t] += red[t + off];
        __syncthreads();
    }
    if (t == 0) blockSum[b] = red[0];
}

// ---------------------------------------------------------------------------
// CSR build step 2b: exclusive scan of block sums (single block)
// ---------------------------------------------------------------------------
__global__ void lgcn_scan_sums(const int* __restrict__ blockSum,
                               int* __restrict__ blockBase,
                               int* __restrict__ row_ptr) {
    int t = threadIdx.x;
    __shared__ int s[256];
    int v = (t < NUM_SCAN_BLOCKS) ? blockSum[t] : 0;
    s[t] = v;
    __syncthreads();
    for (int off = 1; off < 256; off <<= 1) {
        int x = (t >= off) ? s[t - off] : 0;
        __syncthreads();
        s[t] += x;
        __syncthreads();
    }
    if (t < NUM_SCAN_BLOCKS) blockBase[t] = s[t] - v;  // exclusive
    if (t == 0) row_ptr[N_NODES] = NNZ;
}

// ---------------------------------------------------------------------------
// CSR build step 2c: final exclusive scan -> row_ptr[0..N_NODES)
// ---------------------------------------------------------------------------
__global__ void lgcn_scan_final(const int* __restrict__ cnt,
                                const int* __restrict__ blockBase,
                                int* __restrict__ row_ptr) {
    int b = blockIdx.x, t = threadIdx.x;
    int base = b * SCAN_ITEMS + t * 4;
    int v[4];
    int tsum = 0;
#pragma unroll
    for (int k = 0; k < 4; ++k) {
        int i = base + k;
        v[k] = (i < N_NODES) ? cnt[i] : 0;
        tsum += v[k];
    }
    __shared__ int s[256];
    s[t] = tsum;
    __syncthreads();
    for (int off = 1; off < 256; off <<= 1) {
        int x = (t >= off) ? s[t - off] : 0;
        __syncthreads();
        s[t] += x;
        __syncthreads();
    }
    int p = blockBase[b] + (s[t] - tsum);  // exclusive prefix for this thread
#pragma unroll
    for (int k = 0; k < 4; ++k) {
        int i = base + k;
        if (i < N_NODES) row_ptr[i] = p;
        p += v[k];
    }
}

// ---------------------------------------------------------------------------
// CSR build step 3: scatter (col, val) into CSR order — interleaved int2
// (one 8B random write per edge instead of two 4B writes to separate arrays)
// ---------------------------------------------------------------------------
__global__ void lgcn_scatter(const int* __restrict__ row,
                             const int* __restrict__ col,
                             const float* __restrict__ vals,
                             const int* __restrict__ row_ptr,
                             int* __restrict__ cursor,
                             int2* __restrict__ csr_cv) {
    int e = blockIdx.x * blockDim.x + threadIdx.x;
    if (e >= NNZ) return;
    int r = row[e];
    int pos = row_ptr[r] + atomicAdd(&cursor[r], 1);
    csr_cv[pos] = make_int2(col[e], __float_as_int(vals[e]));
}

// ---------------------------------------------------------------------------
// SpMM (pure gather): one wave per row. Lanes = 4 edge-subgroups x 16 chunks.
// Edge loop unrolled x2 with independent accumulators (2 gather chains in
// flight). Fused epilogue: y = A@x row; acc = (acc + y) * scale.
// ---------------------------------------------------------------------------
__global__ __launch_bounds__(256) void lgcn_spmm_csr(
    const int* __restrict__ row_ptr,
    const int2* __restrict__ csr_cv,
    const float* __restrict__ x,
    float4* __restrict__ y,
    float4* __restrict__ acc,
    float scale) {
    int gid = blockIdx.x * blockDim.x + threadIdx.x;
    int r = gid >> 6;
    if (r >= N_NODES) return;
    int lane = threadIdx.x & 63;
    int chunk = lane & 15;   // which float4 of the 64-dim row
    int sub = lane >> 4;     // edge subgroup 0..3

    int start = row_ptr[r];
    int end = row_ptr[r + 1];

    float4 a0 = make_float4(0.f, 0.f, 0.f, 0.f);
    float4 a1 = make_float4(0.f, 0.f, 0.f, 0.f);
    const float4* x4 = (const float4*)x;

    int e = start + sub;
    for (; e + 4 < end; e += 8) {
        int2 cv0 = csr_cv[e];
        int2 cv1 = csr_cv[e + 4];
        float v0 = __int_as_float(cv0.y);
        float v1 = __int_as_float(cv1.y);
        float4 x0 = x4[cv0.x * 16 + chunk];
        float4 x1 = x4[cv1.x * 16 + chunk];
        a0.x += v0 * x0.x; a0.y += v0 * x0.y;
        a0.z += v0 * x0.z; a0.w += v0 * x0.w;
        a1.x += v1 * x1.x; a1.y += v1 * x1.y;
        a1.z += v1 * x1.z; a1.w += v1 * x1.w;
    }
    if (e < end) {
        int2 cv0 = csr_cv[e];
        float v0 = __int_as_float(cv0.y);
        float4 x0 = x4[cv0.x * 16 + chunk];
        a0.x += v0 * x0.x; a0.y += v0 * x0.y;
        a0.z += v0 * x0.z; a0.w += v0 * x0.w;
    }
    float4 a;
    a.x = a0.x + a1.x; a.y = a0.y + a1.y;
    a.z = a0.z + a1.z; a.w = a0.w + a1.w;

    // reduce across the 4 edge subgroups (lanes differing in bits 4,5)
    a.x += __shfl_xor(a.x, 16); a.y += __shfl_xor(a.y, 16);
    a.z += __shfl_xor(a.z, 16); a.w += __shfl_xor(a.w, 16);
    a.x += __shfl_xor(a.x, 32); a.y += __shfl_xor(a.y, 32);
    a.z += __shfl_xor(a.z, 32); a.w += __shfl_xor(a.w, 32);

    if (sub == 0) {
        int idx = r * 16 + chunk;
        y[idx] = a;
        float4 o = acc[idx];
        o.x = (o.x + a.x) * scale;
        o.y = (o.y + a.y) * scale;
        o.z = (o.z + a.z) * scale;
        o.w = (o.w + a.w) * scale;
        acc[idx] = o;
    }
}

extern "C" void kernel_launch(void* const* d_in, const int* in_sizes, int n_in,
                              void* d_out, int out_size, void* d_ws, size_t ws_size,
                              hipStream_t stream) {
    const float* user_emb = (const float*)d_in[0];
    const float* item_emb = (const float*)d_in[1];
    const int*   adj_row  = (const int*)d_in[2];
    const int*   adj_col  = (const int*)d_in[3];
    const float* adj_vals = (const float*)d_in[4];
    float* out = (float*)d_out;

    // workspace layout (~116.4 MB total)
    float* ego_a   = (float*)d_ws;                       // 38.4 MB
    float* ego_b   = ego_a + (size_t)N_NODES * EMB_DIM;  // 38.4 MB
    int*   cnt     = (int*)(ego_b + (size_t)N_NODES * EMB_DIM);  // 600 KB
    int*   row_ptr = cnt + N_NODES;                      // 600 KB
    int*   blockSum  = row_ptr + (N_NODES + 1);          // 1 KB
    int*   blockBase = blockSum + 256;                   // 1 KB
    int2*  csr_cv  = (int2*)(blockBase + 256);           // 38.4 MB interleaved

    // init: ego_a = concat(user,item); out (acc) = same
    {
        int threads = 256;
        int blocks = (N_VEC4 + threads - 1) / threads;
        lgcn_init<<<blocks, threads, 0, stream>>>(
            (const float4*)user_emb, (const float4*)item_emb,
            (float4*)ego_a, (float4*)out);
    }

    // ---- CSR build ----
    hipMemsetAsync(cnt, 0, (size_t)N_NODES * sizeof(int), stream);
    {
        int threads = 256;
        int blocks = (NNZ + threads - 1) / threads;
        lgcn_hist<<<blocks, threads, 0, stream>>>(adj_row, cnt);
    }
    lgcn_scan_blocksums<<<NUM_SCAN_BLOCKS, 256, 0, stream>>>(cnt, blockSum);
    lgcn_scan_sums<<<1, 256, 0, stream>>>(blockSum, blockBase, row_ptr);
    lgcn_scan_final<<<NUM_SCAN_BLOCKS, 256, 0, stream>>>(cnt, blockBase, row_ptr);
    hipMemsetAsync(cnt, 0, (size_t)N_NODES * sizeof(int), stream);  // reuse as cursor
    {
        int threads = 256;
        int blocks = (NNZ + threads - 1) / threads;
        lgcn_scatter<<<blocks, threads, 0, stream>>>(
            adj_row, adj_col, adj_vals, row_ptr, cnt, csr_cv);
    }

    // ---- 3 propagation layers (pure-gather SpMM, fused acc update) ----
    const int spmm_block = 256;                       // 4 waves = 4 rows / block
    const int spmm_grid = (N_NODES * 64 + spmm_block - 1) / spmm_block;
    for (int layer = 0; layer < 3; ++layer) {
        float scale = (layer == 2) ? 0.25f : 1.0f;
        lgcn_spmm_csr<<<spmm_grid, spmm_block, 0, stream>>>(
            row_ptr, csr_cv, ego_a,
            (float4*)ego_b, (float4*)out, scale);
        float* t = ego_a; ego_a = ego_b; ego_b = t;
    }
}